// Round 4
// baseline (155.656 us; speedup 1.0000x reference)
//
#include <hip/hip_runtime.h>
#include <hip/hip_cooperative_groups.h>
#include <math.h>

namespace cg = cooperative_groups;

#define BB 4
#define CC 128
#define KK 32
#define NN 4096
#define NSL 64   // 64-pixel slices

// ---------------------------------------------------------------------------
// K0: per-(k,c) precompute.
// wtS layout: [c][wave][8]: floats 0..3 = w2 for k=4w..4w+3, 4..7 = -2*a*w2
// ---------------------------------------------------------------------------
__launch_bounds__(128)
__global__ void k_prep(const float* __restrict__ anchor, const float* __restrict__ sigp,
                       float* __restrict__ wtS, float* __restrict__ ck,
                       float* __restrict__ inv) {
  const int k = blockIdx.x, c = threadIdx.x;
  float sp = sigp[k * CC + c];
  float s  = 1.0f / (1.0f + expf(-sp));
  float iv = 1.0f / (s + 1e-7f);
  float w2 = iv * iv;
  float a  = anchor[k * CC + c];
  wtS[(c * 8 + (k >> 2)) * 8 + (k & 3)]     = w2;
  wtS[(c * 8 + (k >> 2)) * 8 + 4 + (k & 3)] = -2.0f * a * w2;
  inv[k * CC + c] = iv;
  __shared__ float red[128];
  red[c] = a * a * w2;
  __syncthreads();
  for (int sft = 64; sft > 0; sft >>= 1) {
    if (c < sft) red[c] += red[c + sft];
    __syncthreads();
  }
  if (c == 0) ck[k] = red[0];
}

// ---------------------------------------------------------------------------
struct ScrA {                 // phase 2A (4 blocks)
  float flatL[KK * CC];
  float adjL[KK][36];
  float redp[16][33];
  float n1sqL[KK];
  float denl[KK];
  float n2s;
};
struct ScrB {                 // phase 2B (32 blocks)
  float supL[KK][17];
  float adjL2[KK][33];
};
struct ScrC {                 // phase 3 (all blocks)
  float gbt[KK][136];
};
union Scr { ScrA a; ScrB b2; ScrC c3; };

// ---------------------------------------------------------------------------
// Mega kernel: one cooperative launch, grid (64 slices, 4 b), 512 threads.
// ---------------------------------------------------------------------------
__launch_bounds__(512)
__global__ void k_mega(const float* __restrict__ x, const float* __restrict__ wtS,
                       const float* __restrict__ ck, const float* __restrict__ inv,
                       const float* __restrict__ anchor, const float* __restrict__ W,
                       float* __restrict__ pnum, float* __restrict__ pden,
                       float* __restrict__ flatG, float* __restrict__ adjG,
                       float* __restrict__ GB, float* __restrict__ out) {
  cg::grid_group grid = cg::this_grid();
  const int b = blockIdx.y, s = blockIdx.x;
  const int n0 = s * 64;
  const int t = threadIdx.x;
  const int lane = t & 63;
  const int w = __builtin_amdgcn_readfirstlane(t >> 6);  // wave id 0..7

  __shared__ float lgT[64][40];   // logits [pixel][k]
  __shared__ float stT[64][40];   // soft-assign [pixel][k]
  __shared__ float stK[KK][72];   // soft-assign [k][pixel]
  __shared__ float pdenP[8][33];
  __shared__ Scr scr;

  // ---- P1: logits. wave w owns k = 4w..4w+3; lane = pixel; loop all 128 c.
  {
    float a0 = 0.f, a1 = 0.f, a2 = 0.f, a3 = 0.f;
    const float* xp = x + (size_t)b * CC * NN + n0 + lane;
    const float* wp = wtS + w * 8;
    for (int c = 0; c < CC; c++) {
      float xv = xp[(size_t)c * NN];
      float x2 = xv * xv;
      const float* wc = wp + c * 64;           // wave-uniform -> s_load
      a0 = fmaf(x2, wc[0], fmaf(xv, wc[4], a0));
      a1 = fmaf(x2, wc[1], fmaf(xv, wc[5], a1));
      a2 = fmaf(x2, wc[2], fmaf(xv, wc[6], a2));
      a3 = fmaf(x2, wc[3], fmaf(xv, wc[7], a3));
    }
    float4 lg;
    lg.x = -0.5f * (a0 + ck[w * 4 + 0]);
    lg.y = -0.5f * (a1 + ck[w * 4 + 1]);
    lg.z = -0.5f * (a2 + ck[w * 4 + 2]);
    lg.w = -0.5f * (a3 + ck[w * 4 + 3]);
    *(float4*)&lgT[lane][w * 4] = lg;
  }
  __syncthreads();

  // ---- P2: softmax over k. 8 lanes per pixel (kq quads), shuffle reduce.
  {
    const int p  = w * 8 + (lane >> 3);
    const int kq = lane & 7;
    float4 lv = *(float4*)&lgT[p][kq * 4];
    float m = fmaxf(fmaxf(lv.x, lv.y), fmaxf(lv.z, lv.w));
    m = fmaxf(m, __shfl_xor(m, 1));
    m = fmaxf(m, __shfl_xor(m, 2));
    m = fmaxf(m, __shfl_xor(m, 4));
    float e0 = __expf(lv.x - m), e1 = __expf(lv.y - m);
    float e2 = __expf(lv.z - m), e3 = __expf(lv.w - m);
    float sum = e0 + e1 + e2 + e3;
    sum += __shfl_xor(sum, 1);
    sum += __shfl_xor(sum, 2);
    sum += __shfl_xor(sum, 4);
    float rs = 1.0f / sum;
    e0 *= rs; e1 *= rs; e2 *= rs; e3 *= rs;
    *(float4*)&stT[p][kq * 4] = make_float4(e0, e1, e2, e3);
    stK[kq * 4 + 0][p] = e0;
    stK[kq * 4 + 1][p] = e1;
    stK[kq * 4 + 2][p] = e2;
    stK[kq * 4 + 3][p] = e3;
    float p0 = e0, p1 = e1, p2 = e2, p3 = e3;
    p0 += __shfl_xor(p0, 8);  p1 += __shfl_xor(p1, 8);
    p2 += __shfl_xor(p2, 8);  p3 += __shfl_xor(p3, 8);
    p0 += __shfl_xor(p0, 16); p1 += __shfl_xor(p1, 16);
    p2 += __shfl_xor(p2, 16); p3 += __shfl_xor(p3, 16);
    p0 += __shfl_xor(p0, 32); p1 += __shfl_xor(p1, 32);
    p2 += __shfl_xor(p2, 32); p3 += __shfl_xor(p3, 32);
    if (lane < 8) {
      pdenP[w][lane * 4 + 0] = p0;
      pdenP[w][lane * 4 + 1] = p1;
      pdenP[w][lane * 4 + 2] = p2;
      pdenP[w][lane * 4 + 3] = p3;
    }
  }
  __syncthreads();
  if (t < KK) {
    float d = 0.f;
#pragma unroll
    for (int ww = 0; ww < 8; ww++) d += pdenP[ww][t];
    pden[((size_t)b * NSL + s) * KK + t] = d;
  }

  // ---- P1f: pnum partial GEMM. 2 waves, tile 4k x 8c, x via float4 global.
  if (w < 2) {
    const int kq = t >> 4;   // 0..7
    const int co = t & 15;   // c-base 8*co
    float acc[4][8];
#pragma unroll
    for (int i = 0; i < 4; i++)
#pragma unroll
      for (int j = 0; j < 8; j++) acc[i][j] = 0.f;
    const float* xb = x + (size_t)(b * CC + co * 8) * NN + n0;
    for (int jq = 0; jq < 16; jq++) {
      float4 xr[8];
#pragma unroll
      for (int i = 0; i < 8; i++)
        xr[i] = *(const float4*)(xb + (size_t)i * NN + jq * 4);
#pragma unroll
      for (int jj = 0; jj < 4; jj++) {
        float4 sv = *(float4*)&stT[jq * 4 + jj][kq * 4];
#pragma unroll
        for (int i = 0; i < 8; i++) {
          float xvv = (&xr[i].x)[jj];
          acc[0][i] = fmaf(sv.x, xvv, acc[0][i]);
          acc[1][i] = fmaf(sv.y, xvv, acc[1][i]);
          acc[2][i] = fmaf(sv.z, xvv, acc[2][i]);
          acc[3][i] = fmaf(sv.w, xvv, acc[3][i]);
        }
      }
    }
    float* pp = pnum + ((size_t)(b * NSL + s) * KK + kq * 4) * CC + co * 8;
#pragma unroll
    for (int i = 0; i < 4; i++) {
      *(float4*)(pp + i * CC)     = make_float4(acc[i][0], acc[i][1], acc[i][2], acc[i][3]);
      *(float4*)(pp + i * CC + 4) = make_float4(acc[i][4], acc[i][5], acc[i][6], acc[i][7]);
    }
  }
  grid.sync();

  // ---- P2A: reduce + normalize + adj softmax (4 blocks: s == 0)
  if (s == 0) {
    {
      int sg = t >> 5, kk = t & 31;
      float p = 0.f;
#pragma unroll
      for (int i = 0; i < 4; i++)
        p += pden[((size_t)b * NSL + sg * 4 + i) * KK + kk];
      scr.a.redp[sg][kk] = p;
    }
    const int k = t >> 4, cq = t & 15;
    float4 q0 = make_float4(0.f, 0.f, 0.f, 0.f), q1 = q0;
    const float* pb = pnum + (size_t)b * NSL * KK * CC + k * CC + cq * 8;
#pragma unroll 8
    for (int ss = 0; ss < NSL; ss++) {
      const float4* pv = (const float4*)(pb + (size_t)ss * KK * CC);
      float4 u0 = pv[0], u1 = pv[1];
      q0.x += u0.x; q0.y += u0.y; q0.z += u0.z; q0.w += u0.w;
      q1.x += u1.x; q1.y += u1.y; q1.z += u1.z; q1.w += u1.w;
    }
    __syncthreads();
    if (t < KK) {
      float d = 0.f;
#pragma unroll
      for (int sg = 0; sg < 16; sg++) d += scr.a.redp[sg][t];
      scr.a.denl[t] = d;
    }
    __syncthreads();
    const float dk = scr.a.denl[k];
    const float rden = 1.0f / (dk + 1e-7f);
    const float4* ivp = (const float4*)(inv + k * CC + cq * 8);
    const float4* avp = (const float4*)(anchor + k * CC + cq * 8);
    float4 iv0 = ivp[0], iv1 = ivp[1], av0 = avp[0], av1 = avp[1];
    float4 v0, v1;
    v0.x = iv0.x * (q0.x - av0.x * dk) * rden;
    v0.y = iv0.y * (q0.y - av0.y * dk) * rden;
    v0.z = iv0.z * (q0.z - av0.z * dk) * rden;
    v0.w = iv0.w * (q0.w - av0.w * dk) * rden;
    v1.x = iv1.x * (q1.x - av1.x * dk) * rden;
    v1.y = iv1.y * (q1.y - av1.y * dk) * rden;
    v1.z = iv1.z * (q1.z - av1.z * dk) * rden;
    v1.w = iv1.w * (q1.w - av1.w * dk) * rden;
    float ss2 = v0.x*v0.x + v0.y*v0.y + v0.z*v0.z + v0.w*v0.w
              + v1.x*v1.x + v1.y*v1.y + v1.z*v1.z + v1.w*v1.w;
    ss2 += __shfl_xor(ss2, 1);
    ss2 += __shfl_xor(ss2, 2);
    ss2 += __shfl_xor(ss2, 4);
    ss2 += __shfl_xor(ss2, 8);
    if (cq == 0) scr.a.n1sqL[k] = ss2;
    __syncthreads();
    if (t == 0) {
      float tot = 0.f;
      for (int kk = 0; kk < KK; kk++) {
        float s2 = scr.a.n1sqL[kk];
        float n1 = fmaxf(sqrtf(s2), 1e-12f);
        tot += s2 / (n1 * n1);
      }
      scr.a.n2s = fmaxf(sqrtf(tot), 1e-12f);
    }
    __syncthreads();
    {
      float n1 = fmaxf(sqrtf(scr.a.n1sqL[k]), 1e-12f);
      float sc = 1.0f / (n1 * scr.a.n2s);
      v0.x *= sc; v0.y *= sc; v0.z *= sc; v0.w *= sc;
      v1.x *= sc; v1.y *= sc; v1.z *= sc; v1.w *= sc;
      *(float4*)&scr.a.flatL[k * CC + cq * 8]     = v0;
      *(float4*)&scr.a.flatL[k * CC + cq * 8 + 4] = v1;
      *(float4*)(flatG + (size_t)b * KK * CC + k * CC + cq * 8)     = v0;
      *(float4*)(flatG + (size_t)b * KK * CC + k * CC + cq * 8 + 4) = v1;
    }
    __syncthreads();
    if (t < 64) {   // adj = G^T G on one wave, tile 4x4
      int kq2 = t >> 3, lq = t & 7;
      float aa[4][4];
#pragma unroll
      for (int i = 0; i < 4; i++)
#pragma unroll
        for (int j = 0; j < 4; j++) aa[i][j] = 0.f;
      for (int i2 = 0; i2 < CC; i2++) {
        float4 A  = *(float4*)&scr.a.flatL[i2 * KK + kq2 * 4];
        float4 Bv = *(float4*)&scr.a.flatL[i2 * KK + lq * 4];
#pragma unroll
        for (int i = 0; i < 4; i++) {
          float av = (&A.x)[i];
          aa[i][0] = fmaf(av, Bv.x, aa[i][0]);
          aa[i][1] = fmaf(av, Bv.y, aa[i][1]);
          aa[i][2] = fmaf(av, Bv.z, aa[i][2]);
          aa[i][3] = fmaf(av, Bv.w, aa[i][3]);
        }
      }
#pragma unroll
      for (int i = 0; i < 4; i++)
        *(float4*)&scr.a.adjL[kq2 * 4 + i][lq * 4] =
            make_float4(aa[i][0], aa[i][1], aa[i][2], aa[i][3]);
    }
    __syncthreads();
    if (t < KK) {   // row softmax + write adjG
      float m = -1e30f;
      for (int l = 0; l < KK; l++) m = fmaxf(m, scr.a.adjL[t][l]);
      float sum = 0.f;
      for (int l = 0; l < KK; l++) sum += __expf(scr.a.adjL[t][l] - m);
      float r = 1.0f / sum;
      for (int l = 0; l < KK; l++)
        adjG[((size_t)b * KK + t) * KK + l] = __expf(scr.a.adjL[t][l] - m) * r;
    }
  }
  grid.sync();

  // ---- P2B: support = G^T W, GB = relu(adj @ support)^T (32 blocks)
  if (blockIdx.x >= 8 && blockIdx.x < 16) {
    const int d0 = (blockIdx.x - 8) * 16;
    scr.b2.adjL2[t >> 5][t & 31] = adjG[(size_t)b * KK * KK + t];
    {
      int t2 = t + 512;
      scr.b2.adjL2[t2 >> 5][t2 & 31] = adjG[(size_t)b * KK * KK + t2];
    }
    const int l = t >> 4, d16 = t & 15;
    float accS = 0.f;
    const float* fb = flatG + (size_t)b * KK * CC + l;
    const float* Wb = W + d0 + d16;
#pragma unroll 8
    for (int c = 0; c < CC; c++)
      accS = fmaf(fb[c * KK], Wb[c * CC], accS);
    scr.b2.supL[l][d16] = accS;
    __syncthreads();
    const int kk = t >> 4;
    float g = 0.f;
#pragma unroll
    for (int l2 = 0; l2 < KK; l2++)
      g = fmaf(scr.b2.adjL2[kk][l2], scr.b2.supL[l2][d16], g);
    GB[(size_t)b * KK * CC + (d0 + d16) * KK + kk] = fmaxf(g, 0.f);
  }
  grid.sync();

  // ---- P3: out = GB @ st, reusing this block's own stK tile.
  {
    int k = t & 31, ci = t >> 5;
#pragma unroll
    for (int ii = 0; ii < 8; ii++) {
      int c = ci + ii * 16;
      scr.c3.gbt[k][c] = GB[(size_t)b * KK * CC + c * KK + k];
    }
  }
  __syncthreads();
  if (t < 256) {
    const int cg = t >> 3, ng = t & 7;   // c = 4*cg, n = 8*ng
    float acc[4][8];
#pragma unroll
    for (int i = 0; i < 4; i++)
#pragma unroll
      for (int j = 0; j < 8; j++) acc[i][j] = 0.f;
    for (int k = 0; k < KK; k++) {
      float4 ga = *(float4*)&scr.c3.gbt[k][cg * 4];
      float4 s0 = *(float4*)&stK[k][ng * 8];
      float4 s1 = *(float4*)&stK[k][ng * 8 + 4];
#pragma unroll
      for (int i = 0; i < 4; i++) {
        float gv = (&ga.x)[i];
        acc[i][0] = fmaf(gv, s0.x, acc[i][0]);
        acc[i][1] = fmaf(gv, s0.y, acc[i][1]);
        acc[i][2] = fmaf(gv, s0.z, acc[i][2]);
        acc[i][3] = fmaf(gv, s0.w, acc[i][3]);
        acc[i][4] = fmaf(gv, s1.x, acc[i][4]);
        acc[i][5] = fmaf(gv, s1.y, acc[i][5]);
        acc[i][6] = fmaf(gv, s1.z, acc[i][6]);
        acc[i][7] = fmaf(gv, s1.w, acc[i][7]);
      }
    }
    float* ob = out + (size_t)(b * CC + cg * 4) * NN + n0 + ng * 8;
#pragma unroll
    for (int i = 0; i < 4; i++) {
      *(float4*)(ob + (size_t)i * NN)     = make_float4(acc[i][0], acc[i][1], acc[i][2], acc[i][3]);
      *(float4*)(ob + (size_t)i * NN + 4) = make_float4(acc[i][4], acc[i][5], acc[i][6], acc[i][7]);
    }
  }
}

// ---------------------------------------------------------------------------
extern "C" void kernel_launch(void* const* d_in, const int* in_sizes, int n_in,
                              void* d_out, int out_size, void* d_ws, size_t ws_size,
                              hipStream_t stream) {
  const float* x      = (const float*)d_in[0];
  const float* anchor = (const float*)d_in[1];
  const float* sigp   = (const float*)d_in[2];
  const float* W      = (const float*)d_in[3];
  float* outp = (float*)d_out;

  float* ws    = (float*)d_ws;
  float* wtS   = ws;              //    8192
  float* ckp   = ws + 8192;       //      64
  float* invp  = ws + 8256;       //    4096
  float* pdenp = ws + 12352;      //    8192
  float* pnump = ws + 20544;      // 1048576
  float* flatG = ws + 1069120;    //   16384
  float* adjG  = ws + 1085504;    //    4096
  float* GBp   = ws + 1089600;    //   16384

  k_prep<<<dim3(KK), dim3(CC), 0, stream>>>(anchor, sigp, wtS, ckp, invp);

  void* kargs[] = {(void*)&x, (void*)&wtS, (void*)&ckp, (void*)&invp,
                   (void*)&anchor, (void*)&W, (void*)&pnump, (void*)&pdenp,
                   (void*)&flatG, (void*)&adjG, (void*)&GBp, (void*)&outp};
  hipLaunchCooperativeKernel((const void*)k_mega, dim3(NSL, BB), dim3(512),
                             kargs, 0, stream);
}

// Round 5
// 71.821 us; speedup vs baseline: 2.1673x; 2.1673x over previous
//
#include <hip/hip_runtime.h>
#include <math.h>

#define BB 4
#define CC 128
#define KK 32
#define NN 4096
#define NSL 64   // 64-pixel slices

// ---------------------------------------------------------------------------
// K0: per-(k,c) precompute.
// wtS layout: [c][wave][8]: floats 0..3 = w2 for k=4w..4w+3, 4..7 = -2*a*w2
// ---------------------------------------------------------------------------
__launch_bounds__(128)
__global__ void k_prep(const float* __restrict__ anchor, const float* __restrict__ sigp,
                       float* __restrict__ wtS, float* __restrict__ ck,
                       float* __restrict__ inv) {
  const int k = blockIdx.x, c = threadIdx.x;
  float sp = sigp[k * CC + c];
  float s  = 1.0f / (1.0f + expf(-sp));
  float iv = 1.0f / (s + 1e-7f);
  float w2 = iv * iv;
  float a  = anchor[k * CC + c];
  wtS[(c * 8 + (k >> 2)) * 8 + (k & 3)]     = w2;
  wtS[(c * 8 + (k >> 2)) * 8 + 4 + (k & 3)] = -2.0f * a * w2;
  inv[k * CC + c] = iv;
  __shared__ float red[128];
  red[c] = a * a * w2;
  __syncthreads();
  for (int sft = 64; sft > 0; sft >>= 1) {
    if (c < sft) red[c] += red[c + sft];
    __syncthreads();
  }
  if (c == 0) ck[k] = red[0];
}

// ---------------------------------------------------------------------------
// K1: fused logits + softmax + sa + pnum/pden partials.
// grid (64 slices, 4 b) x 512 threads (8 waves). 64 pixels per block.
//  - x tile staged to LDS once (float4, conflict-free b128 writes)
//  - logits: wave w owns k-quad 4w..4w+3; wt via wave-uniform s_load (SMEM pipe)
//  - softmax: wave-parallel shuffle reduce (8 lanes per pixel)
//  - pnum GEMM: st from LDS b128; x as global float4 (L1-dedup, 2 addrs/wave)
// ---------------------------------------------------------------------------
__launch_bounds__(512)
__global__ void k_A(const float* __restrict__ x, const float* __restrict__ wtS,
                    const float* __restrict__ ck, float* __restrict__ sa,
                    float* __restrict__ pnum, float* __restrict__ pden) {
  const int b  = blockIdx.y, s = blockIdx.x;
  const int n0 = s * 64;
  const int t  = threadIdx.x;
  const int lane = t & 63;
  const int w  = __builtin_amdgcn_readfirstlane(t >> 6);  // wave 0..7

  __shared__ float xt[CC][68];    // x tile [c][pixel]
  __shared__ float lgT[64][40];   // logits [pixel][k]
  __shared__ float stK[KK][68];   // soft-assign [k][pixel]
  __shared__ float pdenP[8][36];

  // ---- stage x tile (32 KB): thread (ct=t>>4, pt=t&15), 4 c-passes
  {
    const int ct = t >> 4, pt = t & 15;
    const float* xb = x + (size_t)b * CC * NN + n0 + 4 * pt;
#pragma unroll
    for (int pass = 0; pass < 4; pass++) {
      int c = ct + pass * 32;
      float4 v = *(const float4*)(xb + (size_t)c * NN);
      *(float4*)&xt[c][4 * pt] = v;
    }
  }
  __syncthreads();

  // ---- logits: lane = pixel, wave w -> k quad; wt via s_load
  {
    float a0 = 0.f, a1 = 0.f, a2 = 0.f, a3 = 0.f;
    const float* wp = wtS + w * 8;
    for (int c = 0; c < CC; c++) {
      float xv = xt[c][lane];
      float x2 = xv * xv;
      const float* wc = wp + c * 64;       // wave-uniform -> SMEM
      a0 = fmaf(x2, wc[0], fmaf(xv, wc[4], a0));
      a1 = fmaf(x2, wc[1], fmaf(xv, wc[5], a1));
      a2 = fmaf(x2, wc[2], fmaf(xv, wc[6], a2));
      a3 = fmaf(x2, wc[3], fmaf(xv, wc[7], a3));
    }
    float4 lg;
    lg.x = -0.5f * (a0 + ck[w * 4 + 0]);
    lg.y = -0.5f * (a1 + ck[w * 4 + 1]);
    lg.z = -0.5f * (a2 + ck[w * 4 + 2]);
    lg.w = -0.5f * (a3 + ck[w * 4 + 3]);
    *(float4*)&lgT[lane][w * 4] = lg;
  }
  __syncthreads();

  // ---- softmax over k: 8 lanes per pixel, shuffle reduce; pden partials
  {
    const int p  = w * 8 + (lane >> 3);
    const int kq = lane & 7;
    float4 lv = *(float4*)&lgT[p][kq * 4];
    float m = fmaxf(fmaxf(lv.x, lv.y), fmaxf(lv.z, lv.w));
    m = fmaxf(m, __shfl_xor(m, 1));
    m = fmaxf(m, __shfl_xor(m, 2));
    m = fmaxf(m, __shfl_xor(m, 4));
    float e0 = __expf(lv.x - m), e1 = __expf(lv.y - m);
    float e2 = __expf(lv.z - m), e3 = __expf(lv.w - m);
    float sum = e0 + e1 + e2 + e3;
    sum += __shfl_xor(sum, 1);
    sum += __shfl_xor(sum, 2);
    sum += __shfl_xor(sum, 4);
    float rs = 1.0f / sum;
    e0 *= rs; e1 *= rs; e2 *= rs; e3 *= rs;
    stK[kq * 4 + 0][p] = e0;
    stK[kq * 4 + 1][p] = e1;
    stK[kq * 4 + 2][p] = e2;
    stK[kq * 4 + 3][p] = e3;
    float p0 = e0, p1 = e1, p2 = e2, p3 = e3;
    p0 += __shfl_xor(p0, 8);  p1 += __shfl_xor(p1, 8);
    p2 += __shfl_xor(p2, 8);  p3 += __shfl_xor(p3, 8);
    p0 += __shfl_xor(p0, 16); p1 += __shfl_xor(p1, 16);
    p2 += __shfl_xor(p2, 16); p3 += __shfl_xor(p3, 16);
    p0 += __shfl_xor(p0, 32); p1 += __shfl_xor(p1, 32);
    p2 += __shfl_xor(p2, 32); p3 += __shfl_xor(p3, 32);
    if (lane < 8) {
      pdenP[w][lane * 4 + 0] = p0;
      pdenP[w][lane * 4 + 1] = p1;
      pdenP[w][lane * 4 + 2] = p2;
      pdenP[w][lane * 4 + 3] = p3;
    }
  }
  __syncthreads();

  // ---- pden write
  if (t < KK) {
    float d = 0.f;
#pragma unroll
    for (int ww = 0; ww < 8; ww++) d += pdenP[ww][t];
    pden[((size_t)b * NSL + s) * KK + t] = d;
  }

  // ---- sa write: thread (k=t>>4, j4=t&15), coalesced float4
  {
    const int k = t >> 4, j4 = t & 15;
    float4 v = *(float4*)&stK[k][4 * j4];
    *(float4*)(sa + ((size_t)b * KK + k) * NN + n0 + 4 * j4) = v;
  }

  // ---- pnum GEMM: thread (k=t&31, cg=t>>5) owns 1k x 8c over 64 n
  {
    const int k = t & 31, cg = t >> 5;
    float acc[8];
#pragma unroll
    for (int i = 0; i < 8; i++) acc[i] = 0.f;
    const float* xb = x + (size_t)(b * CC + cg * 8) * NN + n0;
    for (int j4 = 0; j4 < 16; j4++) {
      float4 sv = *(float4*)&stK[k][4 * j4];
#pragma unroll
      for (int i = 0; i < 8; i++) {
        float4 xr = *(const float4*)(xb + (size_t)i * NN + 4 * j4);
        acc[i] = fmaf(sv.x, xr.x, acc[i]);
        acc[i] = fmaf(sv.y, xr.y, acc[i]);
        acc[i] = fmaf(sv.z, xr.z, acc[i]);
        acc[i] = fmaf(sv.w, xr.w, acc[i]);
      }
    }
    float* pp = pnum + (((size_t)b * NSL + s) * KK + k) * CC + cg * 8;
    *(float4*)pp       = make_float4(acc[0], acc[1], acc[2], acc[3]);
    *(float4*)(pp + 4) = make_float4(acc[4], acc[5], acc[6], acc[7]);
  }
}

// ---------------------------------------------------------------------------
// K2 (full GCN, 1024 threads, 1 block per b) — unchanged from R3 (verified).
// ---------------------------------------------------------------------------
__launch_bounds__(1024)
__global__ void k_gcn(const float* __restrict__ pnum, const float* __restrict__ pden,
                      const float* __restrict__ inv, const float* __restrict__ anchor,
                      const float* __restrict__ W, float* __restrict__ GB) {
  const int b = blockIdx.x;
  const int t = threadIdx.x;
  __shared__ float flat[KK * CC];
  __shared__ float sup[KK][130];
  __shared__ float adjm[KK][33];
  __shared__ float redp[32][33];
  __shared__ float denl[KK], n1v[KK], nsq[KK];
  __shared__ float n2s;

  {
    int kk = t & 31, sg = t >> 5;
    float p = pden[((size_t)b * NSL + sg) * KK + kk]
            + pden[((size_t)b * NSL + 32 + sg) * KK + kk];
    redp[sg][kk] = p;
  }
  __syncthreads();
  if (t < KK) {
    float d = 0.0f;
#pragma unroll
    for (int sg = 0; sg < 32; sg++) d += redp[sg][t];
    denl[t] = d;
  }
  __syncthreads();

  const int k = t >> 5, cq = t & 31;
  const float4* p4 = (const float4*)pnum;
  float4 q = make_float4(0.0f, 0.0f, 0.0f, 0.0f);
#pragma unroll 8
  for (int s = 0; s < NSL; s++) {
    float4 v = p4[((size_t)b * NSL + s) * (KK * CC / 4) + k * 32 + cq];
    q.x += v.x; q.y += v.y; q.z += v.z; q.w += v.w;
  }
  const float dk = denl[k];
  const float rden = 1.0f / (dk + 1e-7f);
  const int idx4 = k * 32 + cq;
  float4 iv = ((const float4*)inv)[idx4];
  float4 av = ((const float4*)anchor)[idx4];
  float4 val;
  val.x = iv.x * (q.x - av.x * dk) * rden;
  val.y = iv.y * (q.y - av.y * dk) * rden;
  val.z = iv.z * (q.z - av.z * dk) * rden;
  val.w = iv.w * (q.w - av.w * dk) * rden;
  redp[cq][k] = val.x * val.x + val.y * val.y + val.z * val.z + val.w * val.w;
  __syncthreads();
  if (t < KK) {
    float s2 = 0.0f;
#pragma unroll
    for (int j = 0; j < 32; j++) s2 += redp[j][t];
    float n1 = fmaxf(sqrtf(s2), 1e-12f);
    n1v[t] = n1;
    nsq[t] = s2 / (n1 * n1);
  }
  __syncthreads();
  if (t == 0) {
    float tot = 0.0f;
#pragma unroll
    for (int kk = 0; kk < KK; kk++) tot += nsq[kk];
    n2s = fmaxf(sqrtf(tot), 1e-12f);
  }
  __syncthreads();
  {
    float sc = 1.0f / (n1v[k] * n2s);
    val.x *= sc; val.y *= sc; val.z *= sc; val.w *= sc;
    ((float4*)flat)[idx4] = val;
  }
  __syncthreads();

  {
    const int k2 = t >> 5, l = t & 31;
    float a = 0.0f;
#pragma unroll 8
    for (int i = 0; i < CC; i++)
      a = fmaf(flat[i * KK + k2], flat[i * KK + l], a);
    adjm[k2][l] = a;
  }
  __syncthreads();
  if (t < KK) {
    float m = -1e30f;
#pragma unroll
    for (int l = 0; l < KK; l++) m = fmaxf(m, adjm[t][l]);
    float s2 = 0.0f;
#pragma unroll
    for (int l = 0; l < KK; l++) { float e = __expf(adjm[t][l] - m); adjm[t][l] = e; s2 += e; }
    float r = 1.0f / s2;
#pragma unroll
    for (int l = 0; l < KK; l++) adjm[t][l] *= r;
  }
  __syncthreads();

  const int d = t & 127, lg = t >> 7;
  float sacc[4] = {0.0f, 0.0f, 0.0f, 0.0f};
  for (int c = 0; c < CC; c++) {
    float wv = W[c * CC + d];
#pragma unroll
    for (int j = 0; j < 4; j++)
      sacc[j] = fmaf(flat[c * KK + lg + 8 * j], wv, sacc[j]);
  }
#pragma unroll
  for (int j = 0; j < 4; j++) sup[lg + 8 * j][d] = sacc[j];
  __syncthreads();

#pragma unroll
  for (int j = 0; j < 4; j++) {
    int kk = lg + 8 * j;
    float g = 0.0f;
#pragma unroll
    for (int l = 0; l < KK; l++) g = fmaf(adjm[kk][l], sup[l][d], g);
    GB[((size_t)b * CC + d) * KK + kk] = fmaxf(g, 0.0f);
  }
}

// ---------------------------------------------------------------------------
// K3: out[b][c][n] = sum_k GB[b][c][k] * sa[b][k][n] — unchanged from R3.
// ---------------------------------------------------------------------------
__launch_bounds__(256)
__global__ void k_proj(const float* __restrict__ GB, const float* __restrict__ sa,
                       float* __restrict__ out) {
  const int b  = blockIdx.y;
  const int n0 = blockIdx.x * 64;
  const int t  = threadIdx.x;
  const int nl = t & 63;
  const int cg = __builtin_amdgcn_readfirstlane(t >> 6);

  float sreg[KK];
  const float* spt = sa + (size_t)b * KK * NN + n0 + nl;
#pragma unroll
  for (int k = 0; k < KK; k++) sreg[k] = spt[(size_t)k * NN];

  const float* gp = GB + ((size_t)b * CC + (size_t)cg * 32) * KK;
  float* op = out + ((size_t)b * CC + (size_t)cg * 32) * NN + n0 + nl;
#pragma unroll 2
  for (int ci = 0; ci < 32; ci++) {
    float acc = 0.0f;
#pragma unroll
    for (int k = 0; k < KK; k++) acc = fmaf(gp[ci * KK + k], sreg[k], acc);
    op[(size_t)ci * NN] = acc;
  }
}

// ---------------------------------------------------------------------------
extern "C" void kernel_launch(void* const* d_in, const int* in_sizes, int n_in,
                              void* d_out, int out_size, void* d_ws, size_t ws_size,
                              hipStream_t stream) {
  const float* x      = (const float*)d_in[0];
  const float* anchor = (const float*)d_in[1];
  const float* sigp   = (const float*)d_in[2];
  const float* W      = (const float*)d_in[3];
  float* out = (float*)d_out;

  float* ws   = (float*)d_ws;
  float* wtS  = ws;               //    8192
  float* ckp  = ws + 8192;        //      64
  float* invp = ws + 8256;        //    4096
  float* pden = ws + 12352;       //    8192
  float* pnum = ws + 20544;       // 1048576
  float* GB   = ws + 1069120;     //   16384
  float* sa   = ws + 1085504;     //  524288

  k_prep<<<dim3(KK),          dim3(128),  0, stream>>>(anchor, sigp, wtS, ckp, invp);
  k_A   <<<dim3(NSL, BB),     dim3(512),  0, stream>>>(x, wtS, ckp, sa, pnum, pden);
  k_gcn <<<dim3(BB),          dim3(1024), 0, stream>>>(pnum, pden, invp, anchor, W, GB);
  k_proj<<<dim3(NN / 64, BB), dim3(256),  0, stream>>>(GB, sa, out);
}

// Round 6
// 65.612 us; speedup vs baseline: 2.3724x; 1.0946x over previous
//
#include <hip/hip_runtime.h>
#include <math.h>

#define BB 4
#define CC 128
#define KK 32
#define NN 4096
#define NSL 64   // 64-pixel slices

__device__ inline float bcastf(float v, int l) {
  return __uint_as_float(__builtin_amdgcn_readlane(__float_as_uint(v), (unsigned)l));
}

// ---------------------------------------------------------------------------
// K1: fused wt-precompute + logits + softmax + sa + pnum/pden partials.
// grid (64 slices, 4 b) x 512 threads (8 waves). 64 pixels per block.
// wave w owns k-quad 4w..4w+3. Lane l holds wt for c=l and c=64+l in VGPRs;
// logits loop broadcasts them via v_readlane (uniform lane index).
// ---------------------------------------------------------------------------
__launch_bounds__(512)
__global__ void k_A(const float* __restrict__ x, const float* __restrict__ anchor,
                    const float* __restrict__ sigp, float* __restrict__ sa,
                    float* __restrict__ pnum, float* __restrict__ pden) {
  const int b  = blockIdx.y, s = blockIdx.x;
  const int n0 = s * 64;
  const int t  = threadIdx.x;
  const int lane = t & 63;
  const int w  = __builtin_amdgcn_readfirstlane(t >> 6);  // wave 0..7

  __shared__ float xt[CC][68];    // x tile [c][pixel]
  __shared__ float lgT[64][40];   // logits [pixel][k]
  __shared__ float stK[KK][68];   // soft-assign [k][pixel]
  __shared__ float pdenP[8][36];

  // ---- stage x tile (32 KB) — issue first so loads fly during wt setup
  {
    const int ct = t >> 4, pt = t & 15;
    const float* xb = x + (size_t)b * CC * NN + n0 + 4 * pt;
#pragma unroll
    for (int pass = 0; pass < 4; pass++) {
      int c = ct + pass * 32;
      float4 v = *(const float4*)(xb + (size_t)c * NN);
      *(float4*)&xt[c][4 * pt] = v;
    }
  }

  // ---- per-wave wt setup: lane l holds (w2, -2*a*w2) for c=l and c=64+l
  float w2a[4], awa[4], w2b[4], awb[4];
  float ck0, ck1, ck2, ck3;
  {
    float cks[4];
#pragma unroll
    for (int i = 0; i < 4; i++) {
      const int k = 4 * w + i;
      float spa = sigp[k * CC + lane];
      float spb = sigp[k * CC + 64 + lane];
      float aa  = anchor[k * CC + lane];
      float ab  = anchor[k * CC + 64 + lane];
      float s1  = 1.0f / (1.0f + expf(-spa));
      float s2  = 1.0f / (1.0f + expf(-spb));
      float iva = 1.0f / (s1 + 1e-7f);
      float ivb = 1.0f / (s2 + 1e-7f);
      w2a[i] = iva * iva;            w2b[i] = ivb * ivb;
      awa[i] = -2.0f * aa * w2a[i];  awb[i] = -2.0f * ab * w2b[i];
      cks[i] = aa * aa * w2a[i] + ab * ab * w2b[i];
    }
#pragma unroll
    for (int d = 1; d < 64; d <<= 1) {
      cks[0] += __shfl_xor(cks[0], d);
      cks[1] += __shfl_xor(cks[1], d);
      cks[2] += __shfl_xor(cks[2], d);
      cks[3] += __shfl_xor(cks[3], d);
    }
    ck0 = cks[0]; ck1 = cks[1]; ck2 = cks[2]; ck3 = cks[3];
  }
  __syncthreads();

  // ---- logits: lane = pixel; wt broadcast via readlane (c uniform)
  {
    float a0 = 0.f, a1 = 0.f, a2 = 0.f, a3 = 0.f;
    for (int c = 0; c < 64; c++) {
      float xv = xt[c][lane];
      float x2 = xv * xv;
      a0 = fmaf(x2, bcastf(w2a[0], c), fmaf(xv, bcastf(awa[0], c), a0));
      a1 = fmaf(x2, bcastf(w2a[1], c), fmaf(xv, bcastf(awa[1], c), a1));
      a2 = fmaf(x2, bcastf(w2a[2], c), fmaf(xv, bcastf(awa[2], c), a2));
      a3 = fmaf(x2, bcastf(w2a[3], c), fmaf(xv, bcastf(awa[3], c), a3));
    }
    for (int c = 0; c < 64; c++) {
      float xv = xt[64 + c][lane];
      float x2 = xv * xv;
      a0 = fmaf(x2, bcastf(w2b[0], c), fmaf(xv, bcastf(awb[0], c), a0));
      a1 = fmaf(x2, bcastf(w2b[1], c), fmaf(xv, bcastf(awb[1], c), a1));
      a2 = fmaf(x2, bcastf(w2b[2], c), fmaf(xv, bcastf(awb[2], c), a2));
      a3 = fmaf(x2, bcastf(w2b[3], c), fmaf(xv, bcastf(awb[3], c), a3));
    }
    float4 lg;
    lg.x = -0.5f * (a0 + ck0);
    lg.y = -0.5f * (a1 + ck1);
    lg.z = -0.5f * (a2 + ck2);
    lg.w = -0.5f * (a3 + ck3);
    *(float4*)&lgT[lane][w * 4] = lg;
  }
  __syncthreads();

  // ---- softmax over k: 8 lanes per pixel, shuffle reduce; pden partials
  {
    const int p  = w * 8 + (lane >> 3);
    const int kq = lane & 7;
    float4 lv = *(float4*)&lgT[p][kq * 4];
    float m = fmaxf(fmaxf(lv.x, lv.y), fmaxf(lv.z, lv.w));
    m = fmaxf(m, __shfl_xor(m, 1));
    m = fmaxf(m, __shfl_xor(m, 2));
    m = fmaxf(m, __shfl_xor(m, 4));
    float e0 = __expf(lv.x - m), e1 = __expf(lv.y - m);
    float e2 = __expf(lv.z - m), e3 = __expf(lv.w - m);
    float sum = e0 + e1 + e2 + e3;
    sum += __shfl_xor(sum, 1);
    sum += __shfl_xor(sum, 2);
    sum += __shfl_xor(sum, 4);
    float rs = 1.0f / sum;
    e0 *= rs; e1 *= rs; e2 *= rs; e3 *= rs;
    stK[kq * 4 + 0][p] = e0;
    stK[kq * 4 + 1][p] = e1;
    stK[kq * 4 + 2][p] = e2;
    stK[kq * 4 + 3][p] = e3;
    float p0 = e0, p1 = e1, p2 = e2, p3 = e3;
    p0 += __shfl_xor(p0, 8);  p1 += __shfl_xor(p1, 8);
    p2 += __shfl_xor(p2, 8);  p3 += __shfl_xor(p3, 8);
    p0 += __shfl_xor(p0, 16); p1 += __shfl_xor(p1, 16);
    p2 += __shfl_xor(p2, 16); p3 += __shfl_xor(p3, 16);
    p0 += __shfl_xor(p0, 32); p1 += __shfl_xor(p1, 32);
    p2 += __shfl_xor(p2, 32); p3 += __shfl_xor(p3, 32);
    if (lane < 8) {
      pdenP[w][lane * 4 + 0] = p0;
      pdenP[w][lane * 4 + 1] = p1;
      pdenP[w][lane * 4 + 2] = p2;
      pdenP[w][lane * 4 + 3] = p3;
    }
  }
  __syncthreads();

  // ---- pden write
  if (t < KK) {
    float d = 0.f;
#pragma unroll
    for (int ww = 0; ww < 8; ww++) d += pdenP[ww][t];
    pden[((size_t)b * NSL + s) * KK + t] = d;
  }

  // ---- sa write: thread (k=t>>4, j4=t&15), coalesced float4
  {
    const int k = t >> 4, j4 = t & 15;
    float4 v = *(float4*)&stK[k][4 * j4];
    *(float4*)(sa + ((size_t)b * KK + k) * NN + n0 + 4 * j4) = v;
  }

  // ---- pnum GEMM: thread (k=t&31, cg=t>>5) owns 1k x 8c over 64 n
  {
    const int k = t & 31, cg = t >> 5;
    float acc[8];
#pragma unroll
    for (int i = 0; i < 8; i++) acc[i] = 0.f;
    const float* xb = x + (size_t)(b * CC + cg * 8) * NN + n0;
    for (int j4 = 0; j4 < 16; j4++) {
      float4 sv = *(float4*)&stK[k][4 * j4];
#pragma unroll
      for (int i = 0; i < 8; i++) {
        float4 xr = *(const float4*)(xb + (size_t)i * NN + 4 * j4);
        acc[i] = fmaf(sv.x, xr.x, acc[i]);
        acc[i] = fmaf(sv.y, xr.y, acc[i]);
        acc[i] = fmaf(sv.z, xr.z, acc[i]);
        acc[i] = fmaf(sv.w, xr.w, acc[i]);
      }
    }
    float* pp = pnum + (((size_t)b * NSL + s) * KK + k) * CC + cg * 8;
    *(float4*)pp       = make_float4(acc[0], acc[1], acc[2], acc[3]);
    *(float4*)(pp + 4) = make_float4(acc[4], acc[5], acc[6], acc[7]);
  }
}

// ---------------------------------------------------------------------------
// K2: full-occupancy reduce of pnum/pden -> unnormalized nodes + n1sq.
// grid = 64 blocks x 256; one thread per (b,k,c). inv computed from sigp.
// ---------------------------------------------------------------------------
__launch_bounds__(256)
__global__ void k_red(const float* __restrict__ pnum, const float* __restrict__ pden,
                      const float* __restrict__ sigp, const float* __restrict__ anchor,
                      float* __restrict__ nodes, float* __restrict__ n1sq) {
  const int t = threadIdx.x;
  const int g = blockIdx.x * 256 + t;
  const int c = g & 127, k = (g >> 7) & 31, b = g >> 12;

  float dk = 0.0f;
#pragma unroll 8
  for (int s = 0; s < NSL; s++) dk += pden[((size_t)b * NSL + s) * KK + k];

  float q = 0.0f;
#pragma unroll 8
  for (int s = 0; s < NSL; s++)
    q += pnum[(((size_t)b * NSL + s) * KK + k) * CC + c];

  const int idx = k * CC + c;
  float sg = 1.0f / (1.0f + expf(-sigp[idx]));
  float iv = 1.0f / (sg + 1e-7f);
  float val = iv * (q - anchor[idx] * dk) / (dk + 1e-7f);
  nodes[((size_t)b * KK + k) * CC + c] = val;

  __shared__ float red[256];
  red[t] = val * val;
  __syncthreads();
  for (int sft = 64; sft > 0; sft >>= 1) {
    if ((t & 127) < sft) red[t] += red[t + sft];
    __syncthreads();
  }
  if ((t & 127) == 0) n1sq[b * KK + k] = red[t];
}

// ---------------------------------------------------------------------------
// K3: normalize + adj softmax + support GEMM + GB. 4 blocks x 1024 threads.
// ---------------------------------------------------------------------------
__launch_bounds__(1024)
__global__ void k_gcn2(const float* __restrict__ nodes, const float* __restrict__ n1sq,
                       const float* __restrict__ W, float* __restrict__ GB) {
  const int b = blockIdx.x;
  const int t = threadIdx.x;
  __shared__ float flat[KK * CC];
  __shared__ float sup[KK][130];
  __shared__ float adjm[KK][33];
  __shared__ float n1v[KK], nsq[KK];
  __shared__ float n2s;

  const int k = t >> 5, cq = t & 31;
  float4 val = ((const float4*)(nodes + (size_t)b * KK * CC))[k * 32 + cq];

  if (t < KK) {
    float s2 = n1sq[b * KK + t];
    float n1 = fmaxf(sqrtf(s2), 1e-12f);
    n1v[t] = n1;
    nsq[t] = s2 / (n1 * n1);
  }
  __syncthreads();
  if (t == 0) {
    float tot = 0.0f;
#pragma unroll
    for (int kk = 0; kk < KK; kk++) tot += nsq[kk];
    n2s = fmaxf(sqrtf(tot), 1e-12f);
  }
  __syncthreads();
  {
    float sc = 1.0f / (n1v[k] * n2s);
    val.x *= sc; val.y *= sc; val.z *= sc; val.w *= sc;
    ((float4*)flat)[k * 32 + cq] = val;
  }
  __syncthreads();

  {  // adj[k2][l] = sum_i flat[i*32+k2]*flat[i*32+l]
    const int k2 = t >> 5, l = t & 31;
    float a = 0.0f;
#pragma unroll 8
    for (int i = 0; i < CC; i++)
      a = fmaf(flat[i * KK + k2], flat[i * KK + l], a);
    adjm[k2][l] = a;
  }
  __syncthreads();
  if (t < KK) {  // row softmax
    float m = -1e30f;
#pragma unroll
    for (int l = 0; l < KK; l++) m = fmaxf(m, adjm[t][l]);
    float s2 = 0.0f;
#pragma unroll
    for (int l = 0; l < KK; l++) { float e = __expf(adjm[t][l] - m); adjm[t][l] = e; s2 += e; }
    float r = 1.0f / s2;
#pragma unroll
    for (int l = 0; l < KK; l++) adjm[t][l] *= r;
  }
  __syncthreads();

  const int d = t & 127, lg = t >> 7;
  float sacc[4] = {0.0f, 0.0f, 0.0f, 0.0f};
  for (int c = 0; c < CC; c++) {
    float wv = W[c * CC + d];
#pragma unroll
    for (int j = 0; j < 4; j++)
      sacc[j] = fmaf(flat[c * KK + lg + 8 * j], wv, sacc[j]);
  }
#pragma unroll
  for (int j = 0; j < 4; j++) sup[lg + 8 * j][d] = sacc[j];
  __syncthreads();

#pragma unroll
  for (int j = 0; j < 4; j++) {
    int kk = lg + 8 * j;
    float g = 0.0f;
#pragma unroll
    for (int l = 0; l < KK; l++) g = fmaf(adjm[kk][l], sup[l][d], g);
    GB[((size_t)b * CC + d) * KK + kk] = fmaxf(g, 0.0f);
  }
}

// ---------------------------------------------------------------------------
// K4: out[b][c][n] = sum_k GB[b][c][k] * sa[b][k][n]
// ---------------------------------------------------------------------------
__launch_bounds__(256)
__global__ void k_proj(const float* __restrict__ GB, const float* __restrict__ sa,
                       float* __restrict__ out) {
  const int b  = blockIdx.y;
  const int n0 = blockIdx.x * 64;
  const int t  = threadIdx.x;
  const int nl = t & 63;
  const int cg = __builtin_amdgcn_readfirstlane(t >> 6);

  float sreg[KK];
  const float* spt = sa + (size_t)b * KK * NN + n0 + nl;
#pragma unroll
  for (int k = 0; k < KK; k++) sreg[k] = spt[(size_t)k * NN];

  const float* gp = GB + ((size_t)b * CC + (size_t)cg * 32) * KK;
  float* op = out + ((size_t)b * CC + (size_t)cg * 32) * NN + n0 + nl;
#pragma unroll 2
  for (int ci = 0; ci < 32; ci++) {
    float acc = 0.0f;
#pragma unroll
    for (int k = 0; k < KK; k++) acc = fmaf(gp[ci * KK + k], sreg[k], acc);
    op[(size_t)ci * NN] = acc;
  }
}

// ---------------------------------------------------------------------------
extern "C" void kernel_launch(void* const* d_in, const int* in_sizes, int n_in,
                              void* d_out, int out_size, void* d_ws, size_t ws_size,
                              hipStream_t stream) {
  const float* x      = (const float*)d_in[0];
  const float* anchor = (const float*)d_in[1];
  const float* sigp   = (const float*)d_in[2];
  const float* W      = (const float*)d_in[3];
  float* out = (float*)d_out;

  float* ws    = (float*)d_ws;
  float* pden  = ws;               //    8192
  float* pnum  = ws + 8192;        // 1048576
  float* nodes = ws + 1056768;     //   16384
  float* n1sq  = ws + 1073152;     //     128
  float* GB    = ws + 1073280;     //   16384
  float* sa    = ws + 1089664;     //  524288

  k_A   <<<dim3(NSL, BB),     dim3(512),  0, stream>>>(x, anchor, sigp, sa, pnum, pden);
  k_red <<<dim3(64),          dim3(256),  0, stream>>>(pnum, pden, sigp, anchor, nodes, n1sq);
  k_gcn2<<<dim3(BB),          dim3(1024), 0, stream>>>(nodes, n1sq, W, GB);
  k_proj<<<dim3(NN / 64, BB), dim3(256),  0, stream>>>(GB, sa, out);
}

// Round 7
// 59.423 us; speedup vs baseline: 2.6194x; 1.1041x over previous
//
#include <hip/hip_runtime.h>
#include <math.h>

#define BB 4
#define CC 128
#define KK 32
#define NN 4096
#define NSL 64   // 64-pixel slices

// ---------------------------------------------------------------------------
// K1: fused wt-precompute + logits + softmax + sa + pnum/pden partials.
// grid (64 slices, 4 b) x 512 threads (8 waves), 64 pixels per block.
//  - wt table computed per block into LDS (redundant, cheap: ~60 ops/thread)
//  - logits: register-tiled: thread = (4px, 2k, c-half); 2 ds_b128 + 16 FMA / c
//  - softmax: wave-parallel shuffle reduce (8 lanes per pixel)
//  - pnum GEMM: st from LDS b128; x as global float4 (L1 dedup)
// ---------------------------------------------------------------------------
__launch_bounds__(512)
__global__ void k_A(const float* __restrict__ x, const float* __restrict__ anchor,
                    const float* __restrict__ sigp, float* __restrict__ sa,
                    float* __restrict__ pnum, float* __restrict__ pden) {
  const int b  = blockIdx.y, s = blockIdx.x;
  const int n0 = s * 64;
  const int t  = threadIdx.x;
  const int lane = t & 63;
  const int w  = __builtin_amdgcn_readfirstlane(t >> 6);  // wave 0..7

  __shared__ float  xt[CC][68];     // x tile [c][pixel]            34.8 KB
  __shared__ float4 wt4[16][129];   // [kpair][c] {w2_0,aw_0,w2_1,aw_1} 33 KB
  __shared__ float  plg[2][64][36]; // partial logits [ch][px][k]   18.4 KB
  __shared__ float  stK[KK][68];    // soft-assign [k][pixel]        8.7 KB
  __shared__ float  ckp[KK][33];    // ck partials                   4.2 KB
  __shared__ float  ckL[KK];
  __shared__ float  pdenP[8][36];

  // ---- stage x tile (32 KB): issue loads first
  {
    const int ct = t >> 4, pt = t & 15;
    const float* xb = x + (size_t)b * CC * NN + n0 + 4 * pt;
#pragma unroll
    for (int pass = 0; pass < 4; pass++) {
      int c = ct + pass * 32;
      float4 v = *(const float4*)(xb + (size_t)c * NN);
      *(float4*)&xt[c][4 * pt] = v;
    }
  }

  // ---- wt table + ck partials (block-local, from sigp/anchor in L2)
  {
    const int base = t * 4;            // entry index into (kp, c) space
    const int kp = base >> 7;          // constant per thread
    const int k0 = kp * 2, k1 = kp * 2 + 1;
    float s0 = 0.f, s1 = 0.f;
#pragma unroll
    for (int e = 0; e < 4; e++) {
      int c = (base + e) & 127;
      float sp0 = sigp[k0 * CC + c], sp1 = sigp[k1 * CC + c];
      float a0  = anchor[k0 * CC + c], a1 = anchor[k1 * CC + c];
      float sg0 = 1.0f / (1.0f + expf(-sp0));
      float sg1 = 1.0f / (1.0f + expf(-sp1));
      float iv0 = 1.0f / (sg0 + 1e-7f), iv1 = 1.0f / (sg1 + 1e-7f);
      float w20 = iv0 * iv0, w21 = iv1 * iv1;
      wt4[kp][c] = make_float4(w20, -2.0f * a0 * w20, w21, -2.0f * a1 * w21);
      s0 = fmaf(a0 * a0, w20, s0);
      s1 = fmaf(a1 * a1, w21, s1);
    }
    ckp[k0][t & 31] = s0;
    ckp[k1][t & 31] = s1;
  }
  __syncthreads();

  if (t < KK) {
    float ssum = 0.f;
#pragma unroll
    for (int j = 0; j < 32; j++) ssum += ckp[t][j];
    ckL[t] = ssum;
  }

  // ---- logits: thread = (px4 = t&15 -> 4 px, kp = (t>>4)&15 -> 2 k, ch = t>>8)
  {
    const int px4 = t & 15, kp = (t >> 4) & 15, ch = t >> 8;
    float acc[8];
#pragma unroll
    for (int i = 0; i < 8; i++) acc[i] = 0.f;
    for (int c0 = 0; c0 < 64; c0++) {
      const int c = ch * 64 + c0;
      float4 xv = *(const float4*)&xt[c][px4 * 4];
      float4 wv = wt4[kp][c];
      acc[0] = fmaf(xv.x, fmaf(xv.x, wv.x, wv.y), acc[0]);
      acc[1] = fmaf(xv.x, fmaf(xv.x, wv.z, wv.w), acc[1]);
      acc[2] = fmaf(xv.y, fmaf(xv.y, wv.x, wv.y), acc[2]);
      acc[3] = fmaf(xv.y, fmaf(xv.y, wv.z, wv.w), acc[3]);
      acc[4] = fmaf(xv.z, fmaf(xv.z, wv.x, wv.y), acc[4]);
      acc[5] = fmaf(xv.z, fmaf(xv.z, wv.z, wv.w), acc[5]);
      acc[6] = fmaf(xv.w, fmaf(xv.w, wv.x, wv.y), acc[6]);
      acc[7] = fmaf(xv.w, fmaf(xv.w, wv.z, wv.w), acc[7]);
    }
#pragma unroll
    for (int i = 0; i < 4; i++) {
      plg[ch][px4 * 4 + i][kp * 2 + 0] = acc[i * 2 + 0];
      plg[ch][px4 * 4 + i][kp * 2 + 1] = acc[i * 2 + 1];
    }
  }
  __syncthreads();

  // ---- softmax over k: 8 lanes per pixel, shuffle reduce; pden partials
  {
    const int p  = w * 8 + (lane >> 3);
    const int kq = lane & 7;
    float4 l0  = *(float4*)&plg[0][p][kq * 4];
    float4 l1  = *(float4*)&plg[1][p][kq * 4];
    float4 ckv = *(float4*)&ckL[kq * 4];
    float4 lv;
    lv.x = -0.5f * (l0.x + l1.x + ckv.x);
    lv.y = -0.5f * (l0.y + l1.y + ckv.y);
    lv.z = -0.5f * (l0.z + l1.z + ckv.z);
    lv.w = -0.5f * (l0.w + l1.w + ckv.w);
    float m = fmaxf(fmaxf(lv.x, lv.y), fmaxf(lv.z, lv.w));
    m = fmaxf(m, __shfl_xor(m, 1));
    m = fmaxf(m, __shfl_xor(m, 2));
    m = fmaxf(m, __shfl_xor(m, 4));
    float e0 = __expf(lv.x - m), e1 = __expf(lv.y - m);
    float e2 = __expf(lv.z - m), e3 = __expf(lv.w - m);
    float sum = e0 + e1 + e2 + e3;
    sum += __shfl_xor(sum, 1);
    sum += __shfl_xor(sum, 2);
    sum += __shfl_xor(sum, 4);
    float rs = 1.0f / sum;
    e0 *= rs; e1 *= rs; e2 *= rs; e3 *= rs;
    stK[kq * 4 + 0][p] = e0;
    stK[kq * 4 + 1][p] = e1;
    stK[kq * 4 + 2][p] = e2;
    stK[kq * 4 + 3][p] = e3;
    float p0 = e0, p1 = e1, p2 = e2, p3 = e3;
    p0 += __shfl_xor(p0, 8);  p1 += __shfl_xor(p1, 8);
    p2 += __shfl_xor(p2, 8);  p3 += __shfl_xor(p3, 8);
    p0 += __shfl_xor(p0, 16); p1 += __shfl_xor(p1, 16);
    p2 += __shfl_xor(p2, 16); p3 += __shfl_xor(p3, 16);
    p0 += __shfl_xor(p0, 32); p1 += __shfl_xor(p1, 32);
    p2 += __shfl_xor(p2, 32); p3 += __shfl_xor(p3, 32);
    if (lane < 8) {
      pdenP[w][lane * 4 + 0] = p0;
      pdenP[w][lane * 4 + 1] = p1;
      pdenP[w][lane * 4 + 2] = p2;
      pdenP[w][lane * 4 + 3] = p3;
    }
  }
  __syncthreads();

  // ---- pden write
  if (t < KK) {
    float d = 0.f;
#pragma unroll
    for (int ww = 0; ww < 8; ww++) d += pdenP[ww][t];
    pden[((size_t)b * NSL + s) * KK + t] = d;
  }

  // ---- sa write: thread (k=t>>4, j4=t&15), coalesced float4
  {
    const int k = t >> 4, j4 = t & 15;
    float4 v = *(float4*)&stK[k][4 * j4];
    *(float4*)(sa + ((size_t)b * KK + k) * NN + n0 + 4 * j4) = v;
  }

  // ---- pnum GEMM: thread (k=t&31, cg=t>>5) owns 1k x 8c over 64 n
  {
    const int k = t & 31, cg = t >> 5;
    float acc[8];
#pragma unroll
    for (int i = 0; i < 8; i++) acc[i] = 0.f;
    const float* xb = x + (size_t)(b * CC + cg * 8) * NN + n0;
    for (int j4 = 0; j4 < 16; j4++) {
      float4 sv = *(float4*)&stK[k][4 * j4];
#pragma unroll
      for (int i = 0; i < 8; i++) {
        float4 xr = *(const float4*)(xb + (size_t)i * NN + 4 * j4);
        acc[i] = fmaf(sv.x, xr.x, acc[i]);
        acc[i] = fmaf(sv.y, xr.y, acc[i]);
        acc[i] = fmaf(sv.z, xr.z, acc[i]);
        acc[i] = fmaf(sv.w, xr.w, acc[i]);
      }
    }
    float* pp = pnum + (((size_t)b * NSL + s) * KK + k) * CC + cg * 8;
    *(float4*)pp       = make_float4(acc[0], acc[1], acc[2], acc[3]);
    *(float4*)(pp + 4) = make_float4(acc[4], acc[5], acc[6], acc[7]);
  }
}

// ---------------------------------------------------------------------------
// K2: full-occupancy reduce of pnum/pden -> unnormalized nodes + n1sq.
// grid = 64 blocks x 256; one thread per (b,k,c). inv computed from sigp.
// ---------------------------------------------------------------------------
__launch_bounds__(256)
__global__ void k_red(const float* __restrict__ pnum, const float* __restrict__ pden,
                      const float* __restrict__ sigp, const float* __restrict__ anchor,
                      float* __restrict__ nodes, float* __restrict__ n1sq) {
  const int t = threadIdx.x;
  const int g = blockIdx.x * 256 + t;
  const int c = g & 127, k = (g >> 7) & 31, b = g >> 12;

  float dk = 0.0f;
#pragma unroll 8
  for (int s = 0; s < NSL; s++) dk += pden[((size_t)b * NSL + s) * KK + k];

  float q = 0.0f;
#pragma unroll 8
  for (int s = 0; s < NSL; s++)
    q += pnum[(((size_t)b * NSL + s) * KK + k) * CC + c];

  const int idx = k * CC + c;
  float sg = 1.0f / (1.0f + expf(-sigp[idx]));
  float iv = 1.0f / (sg + 1e-7f);
  float val = iv * (q - anchor[idx] * dk) / (dk + 1e-7f);
  nodes[((size_t)b * KK + k) * CC + c] = val;

  __shared__ float red[256];
  red[t] = val * val;
  __syncthreads();
  for (int sft = 64; sft > 0; sft >>= 1) {
    if ((t & 127) < sft) red[t] += red[t + sft];
    __syncthreads();
  }
  if ((t & 127) == 0) n1sq[b * KK + k] = red[t];
}

// ---------------------------------------------------------------------------
// K3: normalize + adj softmax + support GEMM + GB. 4 blocks x 1024 threads.
// ---------------------------------------------------------------------------
__launch_bounds__(1024)
__global__ void k_gcn2(const float* __restrict__ nodes, const float* __restrict__ n1sq,
                       const float* __restrict__ W, float* __restrict__ GB) {
  const int b = blockIdx.x;
  const int t = threadIdx.x;
  __shared__ float flat[KK * CC];
  __shared__ float sup[KK][130];
  __shared__ float adjm[KK][33];
  __shared__ float n1v[KK], nsq[KK];
  __shared__ float n2s;

  const int k = t >> 5, cq = t & 31;
  float4 val = ((const float4*)(nodes + (size_t)b * KK * CC))[k * 32 + cq];

  if (t < KK) {
    float s2 = n1sq[b * KK + t];
    float n1 = fmaxf(sqrtf(s2), 1e-12f);
    n1v[t] = n1;
    nsq[t] = s2 / (n1 * n1);
  }
  __syncthreads();
  if (t == 0) {
    float tot = 0.0f;
#pragma unroll
    for (int kk = 0; kk < KK; kk++) tot += nsq[kk];
    n2s = fmaxf(sqrtf(tot), 1e-12f);
  }
  __syncthreads();
  {
    float sc = 1.0f / (n1v[k] * n2s);
    val.x *= sc; val.y *= sc; val.z *= sc; val.w *= sc;
    ((float4*)flat)[k * 32 + cq] = val;
  }
  __syncthreads();

  {  // adj[k2][l] = sum_i flat[i*32+k2]*flat[i*32+l]
    const int k2 = t >> 5, l = t & 31;
    float a = 0.0f;
#pragma unroll 8
    for (int i = 0; i < CC; i++)
      a = fmaf(flat[i * KK + k2], flat[i * KK + l], a);
    adjm[k2][l] = a;
  }
  __syncthreads();
  if (t < KK) {  // row softmax
    float m = -1e30f;
#pragma unroll
    for (int l = 0; l < KK; l++) m = fmaxf(m, adjm[t][l]);
    float s2 = 0.0f;
#pragma unroll
    for (int l = 0; l < KK; l++) { float e = __expf(adjm[t][l] - m); adjm[t][l] = e; s2 += e; }
    float r = 1.0f / s2;
#pragma unroll
    for (int l = 0; l < KK; l++) adjm[t][l] *= r;
  }
  __syncthreads();

  const int d = t & 127, lg = t >> 7;
  float sacc[4] = {0.0f, 0.0f, 0.0f, 0.0f};
  for (int c = 0; c < CC; c++) {
    float wv = W[c * CC + d];
#pragma unroll
    for (int j = 0; j < 4; j++)
      sacc[j] = fmaf(flat[c * KK + lg + 8 * j], wv, sacc[j]);
  }
#pragma unroll
  for (int j = 0; j < 4; j++) sup[lg + 8 * j][d] = sacc[j];
  __syncthreads();

#pragma unroll
  for (int j = 0; j < 4; j++) {
    int kk = lg + 8 * j;
    float g = 0.0f;
#pragma unroll
    for (int l = 0; l < KK; l++) g = fmaf(adjm[kk][l], sup[l][d], g);
    GB[((size_t)b * CC + d) * KK + kk] = fmaxf(g, 0.0f);
  }
}

// ---------------------------------------------------------------------------
// K4: out[b][c][n] = sum_k GB[b][c][k] * sa[b][k][n]
// ---------------------------------------------------------------------------
__launch_bounds__(256)
__global__ void k_proj(const float* __restrict__ GB, const float* __restrict__ sa,
                       float* __restrict__ out) {
  const int b  = blockIdx.y;
  const int n0 = blockIdx.x * 64;
  const int t  = threadIdx.x;
  const int nl = t & 63;
  const int cg = __builtin_amdgcn_readfirstlane(t >> 6);

  float sreg[KK];
  const float* spt = sa + (size_t)b * KK * NN + n0 + nl;
#pragma unroll
  for (int k = 0; k < KK; k++) sreg[k] = spt[(size_t)k * NN];

  const float* gp = GB + ((size_t)b * CC + (size_t)cg * 32) * KK;
  float* op = out + ((size_t)b * CC + (size_t)cg * 32) * NN + n0 + nl;
#pragma unroll 2
  for (int ci = 0; ci < 32; ci++) {
    float acc = 0.0f;
#pragma unroll
    for (int k = 0; k < KK; k++) acc = fmaf(gp[ci * KK + k], sreg[k], acc);
    op[(size_t)ci * NN] = acc;
  }
}

// ---------------------------------------------------------------------------
extern "C" void kernel_launch(void* const* d_in, const int* in_sizes, int n_in,
                              void* d_out, int out_size, void* d_ws, size_t ws_size,
                              hipStream_t stream) {
  const float* x      = (const float*)d_in[0];
  const float* anchor = (const float*)d_in[1];
  const float* sigp   = (const float*)d_in[2];
  const float* W      = (const float*)d_in[3];
  float* out = (float*)d_out;

  float* ws    = (float*)d_ws;
  float* pden  = ws;               //    8192
  float* pnum  = ws + 8192;        // 1048576
  float* nodes = ws + 1056768;     //   16384
  float* n1sq  = ws + 1073152;     //     128
  float* GB    = ws + 1073280;     //   16384
  float* sa    = ws + 1089664;     //  524288

  k_A   <<<dim3(NSL, BB),     dim3(512),  0, stream>>>(x, anchor, sigp, sa, pnum, pden);
  k_red <<<dim3(64),          dim3(256),  0, stream>>>(pnum, pden, sigp, anchor, nodes, n1sq);
  k_gcn2<<<dim3(BB),          dim3(1024), 0, stream>>>(nodes, n1sq, W, GB);
  k_proj<<<dim3(NN / 64, BB), dim3(256),  0, stream>>>(GB, sa, out);
}